// Round 14
// baseline (467.967 us; speedup 1.0000x reference)
//
#include <hip/hip_runtime.h>
#include <hip/hip_bf16.h>

typedef unsigned short u16;
typedef unsigned int u32;
typedef __attribute__((ext_vector_type(8))) short short8;
typedef __attribute__((ext_vector_type(4))) float floatx4;

#define NPIX 12544   // 112*112 = 49 * 256
#define KDIM 768     // channels = 24 * 32
#define EPSF 1e-8f
#define NCH 24       // K chunks of 32 per tile
#define NTILE 49     // 12544 / 256

// ---------------------------------------------------------------- async G->LDS
__device__ __forceinline__ void gload_lds16(const void* g, void* l) {
  __builtin_amdgcn_global_load_lds(
      (const __attribute__((address_space(1))) void*)g,
      (__attribute__((address_space(3))) void*)l, 16, 0, 0);
}

// sortable-uint encoding of float (monotone): max over enc == max over float
__device__ __forceinline__ u32 enc_f32(float f) {
  u32 u = __float_as_uint(f);
  return (u & 0x80000000u) ? ~u : (u | 0x80000000u);
}
__device__ __forceinline__ float dec_f32(u32 e) {
  u32 u = (e & 0x80000000u) ? (e & 0x7FFFFFFFu) : ~e;
  return __uint_as_float(u);
}

// ---------------------------------------------------------------- K0: zero sumsq accumulators + atomic-max buffer
// grid 49, block 256
__global__ void zero_kernel(float* __restrict__ pa, float* __restrict__ pb,
                            u32* __restrict__ part) {
  int i = blockIdx.x * 256 + threadIdx.x;
  pa[i] = 0.f;
  pb[i] = 0.f;
  part[i] = 0u;  // encoded floor (< enc of any finite float)
}

// ---------------------------------------------------------------- K1: transpose + bf16 cast + FUSED sumsq
// (C,N) f32 -> (N,C) bf16, raw values (normalization in GEMM epilogue / finish:
// argmax_j (a_n.b_n) == argmax_j (a.b)*rb[j], cossim = max_j((a.b)*rb[j]) * ra[i], ra,rb>0).
// grid (392, 24, 2), block 256 (=32x8); per (row gi, 32-c block): 32-lane shfl reduce + 1 atomicAdd.
__global__ void transpose_kernel(const float* __restrict__ a, const float* __restrict__ b,
                                 u16* __restrict__ Ar, u16* __restrict__ Br,
                                 float* __restrict__ pa, float* __restrict__ pb) {
  const float* src = blockIdx.z ? b : a;
  u16* dst         = blockIdx.z ? Br : Ar;
  float* psum      = blockIdx.z ? pb : pa;
  __shared__ float tile[32][33];
  int i0 = blockIdx.x * 32;
  int c0 = blockIdx.y * 32;
  int tx = threadIdx.x & 31;
  int ty = threadIdx.x >> 5;  // 0..7
#pragma unroll
  for (int d = 0; d < 4; ++d) {
    int c = c0 + ty + d * 8;
    tile[ty + d * 8][tx] = src[(size_t)c * NPIX + i0 + tx];
  }
  __syncthreads();
#pragma unroll
  for (int d = 0; d < 4; ++d) {
    int il = ty + d * 8;
    int gi = i0 + il;
    float v = tile[tx][il];
    __hip_bfloat16 h = __float2bfloat16(v);
    dst[(size_t)gi * KDIM + c0 + tx] = *reinterpret_cast<u16*>(&h);
    float sq = v * v;
    sq += __shfl_xor(sq, 1);
    sq += __shfl_xor(sq, 2);
    sq += __shfl_xor(sq, 4);
    sq += __shfl_xor(sq, 8);
    sq += __shfl_xor(sq, 16);
    if (tx == 0) atomicAdd(&psum[gi], sq);
  }
}

// ---------------------------------------------------------------- K4: PERSISTENT-BLOCK ring GEMM.
// Round-14: grid (8,32) = 256 blocks = exactly 1/CU. Each block processes the same per-XCD
// tile sequence as r7/r13's balanced decode (idx = jb + 32*r, r=0..9; XCD k owns cols
// {k,k+8,...,k+40} + col-48 share; L2 pinning unchanged). The K-loop is ONE continuous
// chunk stream g = 0..nt*24-1: stages for tile t+1's chunks 0-2 issue during tile t's
// chunks 21-23 under the same vmcnt(4) ledger — the ring NEVER refills between tiles.
// This removes ~9.4 per-CU block lifecycles (3-chunk fill + drain + launch ≈ 8K cyc each
// ≈ 30us total) that the 2401-block grid paid. Slot map invariant: 24%4==0 => slot = g&3.
// Per-tile epilogue uses a DEDICATED 4KB s_max buffer (LDS 132KB, still 1 block/CU) so it
// never touches the live ring; its __syncthreads/rbv-load drain (~500cyc/tile) just lands
// in-flight stages (data stays valid in LDS) — no refill needed after.
// Chunk body r13-exact: R1 {af2 ds_reads | phi1 MFMA + SGB ladder}; vmcnt(4)+bar+schedbar;
// STG(g+3) [slot (g+3)&3 freed: its readers lgkm-drained before this barrier]; R2 {next
// frag reads | phi2 MFMA + SGB ladder}; copies. Tail only at the very last 3 chunks.
// Swizzle (0 conflicts) and lane-linear staging (rule #21) unchanged.
__global__ __launch_bounds__(512, 2) void gemm_max_kernel(const u16* __restrict__ Ar,
                                                          const u16* __restrict__ Br,
                                                          const float* __restrict__ pb,
                                                          u32* __restrict__ part) {
  const int xcd = blockIdx.x;   // 0..7 (linear%8 round-robins XCDs)
  const int jb  = blockIdx.y;   // 0..31: CU slot within XCD

  __shared__ alignas(16) u16 As[4 * 8192];  // 4 ring slots: [256 rows][4 slots][8 elems]
  __shared__ alignas(16) u16 Bs[4 * 8192];
  __shared__ float s_max[1024];             // dedicated epilogue buffer (ring stays live)

  const int tid = threadIdx.x;
  const int lane = tid & 63;
  const int wid = tid >> 6;   // 0..7
  const int wm = wid >> 2;    // A half (0..1)
  const int wn = wid & 3;     // B quarter (0..3)
  const int l15 = lane & 15;
  const int quad = lane >> 4;

  // staging geometry (r13-verified): thread covers rows (tid>>2), (tid>>2)+128, 16B slot
  // tid&3; LDS dest tid*8 / +4096 lane-linear; source pre-swizzled by clog.
  const int srow = tid >> 2;                       // 0..127
  const int clog = ((tid & 3) - (srow >> 1)) & 3;  // logical 8-elem k-group
  u16* lA = &As[tid * 8];
  u16* lB = &Bs[tid * 8];

  // tile decode: r-th tile of this block = idx (jb + 32r) in the per-XCD 301-sequence.
  // Invalid entries occur only at r=9 (prefix property holds).
  auto decode = [&](int r, int& ct, int& rt) -> bool {
    int idx = jb + (r << 5);
    if (idx > 300) return false;
    if (idx < 294) { ct = (idx % 6) * 8 + xcd; rt = idx / 6; return true; }
    int jj = ((idx - 294) << 3) + xcd;
    if (jj >= NTILE) return false;
    ct = 48; rt = jj;
    return true;
  };

  int ct_cur, rt_cur, ct_nxt, rt_nxt, td0, td1;
  const int nt = decode(9, td0, td1) ? 10 : 9;   // 9 or 10 tiles per block
  decode(0, ct_cur, rt_cur);
  if (!decode(1, ct_nxt, rt_nxt)) { ct_nxt = ct_cur; rt_nxt = rt_cur; }

  const u16* sA_cur = Ar + (size_t)(rt_cur * 256 + srow) * KDIM + clog * 8;
  const u16* sB_cur = Br + (size_t)(ct_cur * 256 + srow) * KDIM + clog * 8;
  const u16* sA_nxt = Ar + (size_t)(rt_nxt * 256 + srow) * KDIM + clog * 8;
  const u16* sB_nxt = Br + (size_t)(ct_nxt * 256 + srow) * KDIM + clog * 8;

#define STG(PA, PB, CC, SL)                                                    \
  do {                                                                         \
    gload_lds16((PA) + (CC) * 32,              lA + ((SL) << 13));             \
    gload_lds16((PA) + (CC) * 32 + 128 * KDIM, lA + ((SL) << 13) + 4096);     \
    gload_lds16((PB) + (CC) * 32,              lB + ((SL) << 13));             \
    gload_lds16((PB) + (CC) * 32 + 128 * KDIM, lB + ((SL) << 13) + 4096);     \
  } while (0)

  // frag element offsets within a slot: row R, k-quad quad -> R*32 + (((R>>1)+quad)&3)*8
  int aoff[8], boff[4];
#pragma unroll
  for (int mm = 0; mm < 8; ++mm) {
    int R = wm * 128 + mm * 16 + l15;
    aoff[mm] = R * 32 + ((((R >> 1) + quad) & 3) << 3);
  }
#pragma unroll
  for (int nf = 0; nf < 4; ++nf) {
    int Cc = wn * 64 + nf * 16 + l15;
    boff[nf] = Cc * 32 + ((((Cc >> 1) + quad) & 3) << 3);
  }

  floatx4 acc[8][4];
#pragma unroll
  for (int m = 0; m < 8; ++m)
#pragma unroll
    for (int n = 0; n < 4; ++n) acc[m][n] = (floatx4){0.f, 0.f, 0.f, 0.f};

  // per-tile epilogue: scale by rb[col], row-max, atomicMax; reset acc.
  // C frag layout: col = l15 (+nf*16), row = quad*4 + rr (+m*16, +wm*128).
  auto epilogue = [&](int rowb, int colb) {
    float rbv[4];
#pragma unroll
    for (int nf = 0; nf < 4; ++nf) {
      float s = pb[colb + wn * 64 + nf * 16 + l15];
      rbv[nf] = 1.f / (sqrtf(s + EPSF) + EPSF);
    }
#pragma unroll
    for (int m = 0; m < 8; ++m) {
#pragma unroll
      for (int rr = 0; rr < 4; ++rr) {
        float best = fmaxf(fmaxf(acc[m][0][rr] * rbv[0], acc[m][1][rr] * rbv[1]),
                           fmaxf(acc[m][2][rr] * rbv[2], acc[m][3][rr] * rbv[3]));
        best = fmaxf(best, __shfl_xor(best, 1));
        best = fmaxf(best, __shfl_xor(best, 2));
        best = fmaxf(best, __shfl_xor(best, 4));
        best = fmaxf(best, __shfl_xor(best, 8));
        if (l15 == 0)
          s_max[wn * 256 + wm * 128 + m * 16 + quad * 4 + rr] = best;  // unique writer
      }
    }
    __syncthreads();
    if (tid < 256) {
      float mx = fmaxf(fmaxf(s_max[tid], s_max[256 + tid]),
                       fmaxf(s_max[512 + tid], s_max[768 + tid]));
      atomicMax(&part[rowb + tid], enc_f32(mx));
    }
#pragma unroll
    for (int m = 0; m < 8; ++m)
#pragma unroll
      for (int n = 0; n < 4; ++n) acc[m][n] = (floatx4){0.f, 0.f, 0.f, 0.f};
  };

  // prologue: stage chunks 0,1,2 of tile 0; vmcnt(8) = chunk 0 landed (1,2 in flight)
  STG(sA_cur, sB_cur, 0, 0); STG(sA_cur, sB_cur, 1, 1); STG(sA_cur, sB_cur, 2, 2);
  asm volatile("s_waitcnt vmcnt(8)" ::: "memory");
  __builtin_amdgcn_s_barrier();
  __builtin_amdgcn_sched_barrier(0);

  short8 afc[4], bfc[4];
#pragma unroll
  for (int mm = 0; mm < 4; ++mm) afc[mm] = *(const short8*)&As[aoff[mm]];
#pragma unroll
  for (int nf = 0; nf < 4; ++nf) bfc[nf] = *(const short8*)&Bs[boff[nf]];

  const int Ntot = nt * NCH;   // 216 or 240 chunks
  int c = 0, rtile = 0;
  for (int g = 0; g < Ntot - 1; ++g) {
    const int slot = g & 3;    // == c & 3 (24 % 4 == 0)
    const u16* pAs = &As[slot << 13];
    const u16* pAn = &As[((slot + 1) & 3) << 13];
    const u16* pBn = &Bs[((slot + 1) & 3) << 13];
    short8 af2[4], afn[4], bfn[4];

    // R1: af2 reads (slot g) || phi1 MFMA (afc,bfc ready in regs)
#pragma unroll
    for (int mm = 0; mm < 4; ++mm) af2[mm] = *(const short8*)&pAs[aoff[mm + 4]];
#pragma unroll
    for (int mm = 0; mm < 4; ++mm)
#pragma unroll
      for (int nf = 0; nf < 4; ++nf)
        acc[mm][nf] = __builtin_amdgcn_mfma_f32_16x16x32_bf16(afc[mm], bfc[nf], acc[mm][nf], 0, 0, 0);
#pragma unroll
    for (int gg = 0; gg < 4; ++gg) {
      __builtin_amdgcn_sched_group_barrier(0x100, 1, 0); /* 1 ds_read */
      __builtin_amdgcn_sched_group_barrier(0x008, 4, 0); /* 4 mfma    */
    }

    // counted wait + barrier: chunk g+1 landed; slot (g+3)&3 readers all done
    if (g < Ntot - 2) {
      asm volatile("s_waitcnt vmcnt(4)" ::: "memory");
    } else {
      asm volatile("s_waitcnt vmcnt(0)" ::: "memory");
    }
    __builtin_amdgcn_s_barrier();
    __builtin_amdgcn_sched_barrier(0);

    // stage chunk g+3 (cross-tile: chunks 21-23 stage next tile's 0-2)
    if (g + 3 < Ntot) {
      int cc = c + 3;
      if (cc < NCH) STG(sA_cur, sB_cur, cc, (slot + 3) & 3);
      else          STG(sA_nxt, sB_nxt, cc - NCH, (slot + 3) & 3);
    }

    // R2: next-chunk frag reads (slot g+1) || phi2 MFMA (af2 from R1, lgkm-covered)
#pragma unroll
    for (int mm = 0; mm < 4; ++mm) afn[mm] = *(const short8*)&pAn[aoff[mm]];
#pragma unroll
    for (int nf = 0; nf < 4; ++nf) bfn[nf] = *(const short8*)&pBn[boff[nf]];
#pragma unroll
    for (int mm = 0; mm < 4; ++mm)
#pragma unroll
      for (int nf = 0; nf < 4; ++nf)
        acc[mm + 4][nf] = __builtin_amdgcn_mfma_f32_16x16x32_bf16(af2[mm], bfc[nf], acc[mm + 4][nf], 0, 0, 0);
#pragma unroll
    for (int gg = 0; gg < 8; ++gg) {
      __builtin_amdgcn_sched_group_barrier(0x100, 1, 0); /* 1 ds_read */
      __builtin_amdgcn_sched_group_barrier(0x008, 2, 0); /* 2 mfma    */
    }
#pragma unroll
    for (int mm = 0; mm < 4; ++mm) afc[mm] = afn[mm];
#pragma unroll
    for (int nf = 0; nf < 4; ++nf) bfc[nf] = bfn[nf];

    // tile boundary (never the global last chunk: that one is peeled below)
    if (c == NCH - 1) {
      epilogue(rt_cur * 256, ct_cur * 256);
      // rotate staging tiles: cur <- nxt, nxt <- decode(rtile+2)
      sA_cur = sA_nxt; sB_cur = sB_nxt; rt_cur = rt_nxt; ct_cur = ct_nxt;
      int tc, tr;
      if (decode(rtile + 2, tc, tr)) {
        rt_nxt = tr; ct_nxt = tc;
        sA_nxt = Ar + (size_t)(tr * 256 + srow) * KDIM + clog * 8;
        sB_nxt = Br + (size_t)(tc * 256 + srow) * KDIM + clog * 8;
      }
      ++rtile; c = 0;
    } else {
      ++c;
    }
  }

  // peeled last chunk (g = Ntot-1, slot 3): frags afc/bfc from the loop's final R2
  {
    const u16* pAs = &As[3 << 13];
    short8 af2[4];
#pragma unroll
    for (int mm = 0; mm < 4; ++mm) af2[mm] = *(const short8*)&pAs[aoff[mm + 4]];
#pragma unroll
    for (int mm = 0; mm < 4; ++mm)
#pragma unroll
      for (int nf = 0; nf < 4; ++nf)
        acc[mm][nf] = __builtin_amdgcn_mfma_f32_16x16x32_bf16(afc[mm], bfc[nf], acc[mm][nf], 0, 0, 0);
#pragma unroll
    for (int mm = 0; mm < 4; ++mm)
#pragma unroll
      for (int nf = 0; nf < 4; ++nf)
        acc[mm + 4][nf] = __builtin_amdgcn_mfma_f32_16x16x32_bf16(af2[mm], bfc[nf], acc[mm + 4][nf], 0, 0, 0);
  }
  epilogue(rt_cur * 256, ct_cur * 256);

#undef STG
}

// ---------------------------------------------------------------- K5: decode + apply ra + loss
// single block, 1024 threads; ra computed inline from pa.
__global__ void finish_kernel(const u32* __restrict__ part, const float* __restrict__ pa,
                              float* __restrict__ out) {
  float v = 0.f;
  for (int i = threadIdx.x; i < NPIX; i += 1024) {
    float ra = 1.f / (sqrtf(pa[i] + EPSF) + EPSF);
    v += 1.0f - dec_f32(part[i]) * ra;
  }
#pragma unroll
  for (int off = 32; off > 0; off >>= 1) v += __shfl_down(v, off);
  __shared__ float red[16];
  int w = threadIdx.x >> 6;
  if ((threadIdx.x & 63) == 0) red[w] = v;
  __syncthreads();
  if (threadIdx.x == 0) {
    float s = 0.f;
#pragma unroll
    for (int k = 0; k < 16; ++k) s += red[k];
    out[0] = s * (1.0f / (float)NPIX);
  }
}

// ---------------------------------------------------------------- launcher
extern "C" void kernel_launch(void* const* d_in, const int* in_sizes, int n_in,
                              void* d_out, int out_size, void* d_ws, size_t ws_size,
                              hipStream_t stream) {
  const float* x = (const float*)d_in[0];
  const float* s = (const float*)d_in[1];
  char* ws = (char*)d_ws;
  // layout (bytes):
  float* pa   = (float*)(ws + 0);         //    50176 (sumsq accum)
  float* pb   = (float*)(ws + 401408);    //    50176
  u32*   part = (u32*)  (ws + 903168);    //    50176 (encoded row maxima)
  u16*   Ar   = (u16*)  (ws + 953344);    // 19267584
  u16*   Br   = (u16*)  (ws + 20220928);  // 19267584  -> total 39488512 B

  zero_kernel<<<49, 256, 0, stream>>>(pa, pb, part);
  transpose_kernel<<<dim3(392, 24, 2), 256, 0, stream>>>(x, s, Ar, Br, pa, pb);
  gemm_max_kernel<<<dim3(8, 32), 512, 0, stream>>>(Ar, Br, pb, part);
  finish_kernel<<<1, 1024, 0, stream>>>(part, pa, (float*)d_out);
}